// Round 3
// baseline (591.540 us; speedup 1.0000x reference)
//
#include <hip/hip_runtime.h>
#include <hip/hip_bf16.h>
#include <stdint.h>

// GGUF Q8_0-style quantized linear: C[M,N] = A[M,K] * W[K,N] + bias[N]
//   W[k][n] = q[k][n] * scales[k][n>>5]
// M = 8192, K = 4096, N = 4096.
//
// Two-pass:
//   pass 1 (merged): A fp32->bf16  +  dequant/transpose W -> Wt[N][K] bf16
//   pass 2: bf16 MFMA GEMM, 128x128 tile, BK=64, global_load_lds width=16,
//           XOR-swizzled LDS so ds_read_b128 stays at minimum bank aliasing.

#define M_DIM 8192
#define N_DIM 4096
#define K_DIM 4096
#define NBLK  128   // N / 32

typedef __attribute__((ext_vector_type(8))) short short8;   // 8 bf16
typedef __attribute__((ext_vector_type(4))) float f32x4;

typedef const __attribute__((address_space(1))) unsigned char* gas;
typedef __attribute__((address_space(3))) unsigned char* las;

// Pack two fp32 into two bf16 (RNE): low = a, high = b.
__device__ __forceinline__ unsigned pk_bf16(float a, float b) {
  unsigned ua = __builtin_bit_cast(unsigned, a);
  unsigned ub = __builtin_bit_cast(unsigned, b);
  ua += 0x7fffu + ((ua >> 16) & 1u);
  ub += 0x7fffu + ((ub >> 16) & 1u);
  return (ua >> 16) | (ub & 0xffff0000u);
}

// ---------------- pass 1 (merged): A convert + W dequant/transpose ----------
// Blocks [0, 16384): A fp32 -> bf16, 8 elems/thread.
// Blocks [16384, 20480): 64x64 dequant+transpose tiles through LDS.
__global__ __launch_bounds__(256)
void prep(const float* __restrict__ A, const int* __restrict__ Q,
          const float* __restrict__ S, ushort* __restrict__ Abf,
          ushort* __restrict__ Wt) {
  __shared__ ushort T[64 * 68];
  const int t = threadIdx.x;
  if (blockIdx.x < 16384) {
    const long idx = ((long)blockIdx.x * 256 + t) * 8;
    const float4 v0 = *(const float4*)(A + idx);
    const float4 v1 = *(const float4*)(A + idx + 4);
    uint4 p;
    p.x = pk_bf16(v0.x, v0.y);
    p.y = pk_bf16(v0.z, v0.w);
    p.z = pk_bf16(v1.x, v1.y);
    p.w = pk_bf16(v1.z, v1.w);
    *(uint4*)(Abf + idx) = p;
  } else {
    const int bid = blockIdx.x - 16384;
    const int n0 = (bid & 63) * 64;
    const int k0 = (bid >> 6) * 64;
    const int nl = t & 63;   // lane-over-n: coalesced Q reads
    const int kb = t >> 6;   // 0..3
    #pragma unroll
    for (int i = 0; i < 16; ++i) {
      const int kl = kb + i * 4;
      const int k = k0 + kl;
      const int q = Q[(long)k * N_DIM + n0 + nl];
      const float s = S[k * NBLK + ((n0 + nl) >> 5)];
      const float w = (float)q * s;
      unsigned u = __builtin_bit_cast(unsigned, w);
      u += 0x7fffu + ((u >> 16) & 1u);
      T[nl * 68 + kl] = (ushort)(u >> 16);
    }
    __syncthreads();
    const int n = t >> 2;         // 0..63
    const int kc = (t & 3) * 16;  // 0,16,32,48
    const ushort* src = &T[n * 68 + kc];
    uint2 a = *(const uint2*)(src + 0);
    uint2 b = *(const uint2*)(src + 4);
    uint2 c = *(const uint2*)(src + 8);
    uint2 d = *(const uint2*)(src + 12);
    uint4 o0 = {a.x, a.y, b.x, b.y};
    uint4 o1 = {c.x, c.y, d.x, d.y};
    ushort* dst = Wt + (long)(n0 + n) * K_DIM + k0 + kc;
    *(uint4*)(dst + 0) = o0;
    *(uint4*)(dst + 8) = o1;
  }
}

// ---------------- pass 2: BK=64 bf16 GEMM ----------------
// LDS layout per operand: 128 rows x 64 ushorts (8 chunks of 8 bf16).
// Data (row r, chunk c) lives at chunk-position c ^ (r&7) — XOR swizzle folded
// into the *global* fetch address of global_load_lds (LDS side must stay
// lane-contiguous). Gives uniform 8 touches/bank for all ds_read_b128.
__global__ __launch_bounds__(256)
void gemm_bf16(const ushort* __restrict__ Abf, const ushort* __restrict__ Wt,
               const float* __restrict__ bias, float* __restrict__ C) {
  __shared__ __align__(16) ushort Alds[128 * 64];
  __shared__ __align__(16) ushort Blds[128 * 64];

  const int tid = threadIdx.x;
  const int m0 = blockIdx.y * 128;
  const int n0 = blockIdx.x * 128;
  const int wave = tid >> 6;
  const int lane = tid & 63;
  const int wm = (wave >> 1) * 64;
  const int wn = (wave & 1) * 64;
  const int lrow = lane & 15;
  const int quad = lane >> 4;

  // Staging: instr (wave, i) fills rows [wave*8 + i*32, +8).
  // Lane l = (local row r = l>>3, chunk-position p = l&7) -> fetches global
  // chunk c = p ^ r.
  const int srow = wave * 8 + (lane >> 3);
  const int schunk = (lane & 7) ^ ((lane >> 3) & 7);

  const ushort* Ag = Abf + (long)(m0 + srow) * K_DIM + schunk * 8;
  const ushort* Bg = Wt + (long)(n0 + srow) * K_DIM + schunk * 8;

  f32x4 acc[4][4];
  #pragma unroll
  for (int i = 0; i < 4; ++i)
    #pragma unroll
    for (int j = 0; j < 4; ++j)
      acc[i][j] = (f32x4){0.f, 0.f, 0.f, 0.f};

  const int pswz = (quad ^ (lane & 7)) * 8;  // chunk-position for h=0, *8 elems

  for (int k0 = 0; k0 < K_DIM; k0 += 64) {
    #pragma unroll
    for (int i = 0; i < 4; ++i) {
      __builtin_amdgcn_global_load_lds((gas)(Ag + (long)i * 32 * K_DIM + k0),
                                       (las)&Alds[(wave * 8 + i * 32) * 64], 16, 0, 0);
      __builtin_amdgcn_global_load_lds((gas)(Bg + (long)i * 32 * K_DIM + k0),
                                       (las)&Blds[(wave * 8 + i * 32) * 64], 16, 0, 0);
    }
    __syncthreads();

    #pragma unroll
    for (int h = 0; h < 2; ++h) {
      const int pb = pswz ^ (h << 5);  // ((quad^(lane&7)) ^ (h<<2)) * 8
      short8 af[4], bf[4];
      #pragma unroll
      for (int t = 0; t < 4; ++t) {
        af[t] = *(const short8*)&Alds[(wm + t * 16 + lrow) * 64 + pb];
        bf[t] = *(const short8*)&Blds[(wn + t * 16 + lrow) * 64 + pb];
      }
      #pragma unroll
      for (int mt = 0; mt < 4; ++mt)
        #pragma unroll
        for (int nt = 0; nt < 4; ++nt)
          acc[mt][nt] = __builtin_amdgcn_mfma_f32_16x16x32_bf16(af[mt], bf[nt],
                                                                acc[mt][nt], 0, 0, 0);
    }
    __syncthreads();
  }

  // Epilogue: C/D layout row = quad*4+reg, col = lane&15 (verified r1/r2).
  #pragma unroll
  for (int nt = 0; nt < 4; ++nt) {
    const int n = n0 + wn + nt * 16 + lrow;
    const float bv = bias[n];
    #pragma unroll
    for (int mt = 0; mt < 4; ++mt) {
      const int mbase = m0 + wm + mt * 16 + quad * 4;
      #pragma unroll
      for (int r = 0; r < 4; ++r) {
        C[(long)(mbase + r) * N_DIM + n] = acc[mt][nt][r] + bv;
      }
    }
  }
}

// ---------------- fallback (round-1 fused kernel, ws-less) ----------------
__global__ __launch_bounds__(256)
void gguf_gemm_fused(const float* __restrict__ A, const int* __restrict__ Q,
                     const float* __restrict__ S, const float* __restrict__ bias,
                     float* __restrict__ C) {
  __shared__ __align__(16) ushort Alds[128 * 32];
  __shared__ __align__(16) ushort Blds[128 * 32];
  const int tid = threadIdx.x;
  const int m0 = blockIdx.y * 128;
  const int n0 = blockIdx.x * 128;
  const int wave = tid >> 6, lane = tid & 63;
  const int wm = (wave >> 1) * 64, wn = (wave & 1) * 64;
  const int lrow = lane & 15, quad = lane >> 4;
  const int ar = tid >> 2, ac = (tid & 3) * 4;
  const int c8a = ((ar >> 1) & 3) << 3;
  const int bn = tid & 127, bkc = (tid >> 7) * 16;
  const int c8b = ((bn >> 1) & 3) << 3;
  const float* Abase = A + (long)(m0 + ar) * K_DIM + ac;
  const int* Qbase = Q + (long)bkc * N_DIM + n0 + bn;
  const float* Sbase = S + (long)bkc * NBLK + ((n0 + bn) >> 5);
  f32x4 acc[4][4];
  #pragma unroll
  for (int i = 0; i < 4; ++i)
    #pragma unroll
    for (int j = 0; j < 4; ++j) acc[i][j] = (f32x4){0.f, 0.f, 0.f, 0.f};
  for (int k0 = 0; k0 < K_DIM; k0 += 32) {
    #pragma unroll
    for (int i = 0; i < 2; ++i)
      #pragma unroll
      for (int j = 0; j < 2; ++j) {
        const float4 v = *(const float4*)(Abase + (long)i * 64 * K_DIM + k0 + j * 16);
        uint2 p; p.x = pk_bf16(v.x, v.y); p.y = pk_bf16(v.z, v.w);
        const int k = ac + j * 16;
        *(uint2*)&Alds[(ar + i * 64) * 32 + (k ^ c8a)] = p;
      }
    {
      const int* qp = Qbase + (long)k0 * N_DIM;
      const float* sp = Sbase + (long)k0 * NBLK;
      unsigned w[8];
      #pragma unroll
      for (int i = 0; i < 8; ++i) {
        const int q0 = qp[(2 * i) * N_DIM];
        const int q1 = qp[(2 * i + 1) * N_DIM];
        const float s0 = sp[(2 * i) * NBLK];
        const float s1 = sp[(2 * i + 1) * NBLK];
        w[i] = pk_bf16((float)q0 * s0, (float)q1 * s1);
      }
      uint4 g0 = {w[0], w[1], w[2], w[3]};
      uint4 g1 = {w[4], w[5], w[6], w[7]};
      *(uint4*)&Blds[bn * 32 + (bkc ^ c8b)] = g0;
      *(uint4*)&Blds[bn * 32 + ((bkc + 8) ^ c8b)] = g1;
    }
    __syncthreads();
    short8 afrag[4], bfrag[4];
    #pragma unroll
    for (int t = 0; t < 4; ++t) {
      const int mrow = wm + t * 16 + lrow;
      afrag[t] = *(const short8*)&Alds[mrow * 32 + ((quad * 8) ^ (((mrow >> 1) & 3) << 3))];
      const int nrow = wn + t * 16 + lrow;
      bfrag[t] = *(const short8*)&Blds[nrow * 32 + ((quad * 8) ^ (((nrow >> 1) & 3) << 3))];
    }
    #pragma unroll
    for (int mt = 0; mt < 4; ++mt)
      #pragma unroll
      for (int nt = 0; nt < 4; ++nt)
        acc[mt][nt] = __builtin_amdgcn_mfma_f32_16x16x32_bf16(afrag[mt], bfrag[nt],
                                                              acc[mt][nt], 0, 0, 0);
    __syncthreads();
  }
  #pragma unroll
  for (int nt = 0; nt < 4; ++nt) {
    const int n = n0 + wn + nt * 16 + lrow;
    const float bv = bias[n];
    #pragma unroll
    for (int mt = 0; mt < 4; ++mt) {
      const int mbase = m0 + wm + mt * 16 + quad * 4;
      #pragma unroll
      for (int r = 0; r < 4; ++r)
        C[(long)(mbase + r) * N_DIM + n] = acc[mt][nt][r] + bv;
    }
  }
}

extern "C" void kernel_launch(void* const* d_in, const int* in_sizes, int n_in,
                              void* d_out, int out_size, void* d_ws, size_t ws_size,
                              hipStream_t stream) {
  const float* A    = (const float*)d_in[0];
  const int*   Q    = (const int*)d_in[1];
  const float* S    = (const float*)d_in[2];
  const float* bias = (const float*)d_in[3];
  float* C = (float*)d_out;

  const size_t abf_bytes = (size_t)M_DIM * K_DIM * 2;   // 64 MiB
  const size_t wt_bytes  = (size_t)N_DIM * K_DIM * 2;   // 32 MiB

  if (ws_size >= abf_bytes + wt_bytes) {
    ushort* Abf = (ushort*)d_ws;
    ushort* Wt  = (ushort*)((char*)d_ws + abf_bytes);
    prep<<<16384 + 4096, 256, 0, stream>>>(A, Q, S, Abf, Wt);
    dim3 grid(N_DIM / 128, M_DIM / 128);
    gemm_bf16<<<grid, 256, 0, stream>>>(Abf, Wt, bias, C);
  } else {
    dim3 grid(N_DIM / 128, M_DIM / 128);
    gguf_gemm_fused<<<grid, 256, 0, stream>>>(A, Q, S, bias, C);
  }
}